// Round 19
// baseline (32.605 us; speedup 1.0000x reference)
//
#include <hip/hip_runtime.h>
#include <hip/hip_bf16.h>
#include <stdint.h>

// SVR polynomial-kernel prediction:
//   out[m] = sum_n alpha[n] * (1 + x_p[m].X[n])^4 + b
// m=16384, n=8192, d=64, all fp32 in/out.
// R19 = R18 (best, 31.9us) + CHUNK=128 (two 64-col halves per barrier):
//   - 64 MFMA per wave between barriers (was 32); barriers 16 -> 8
//   - deferred epilogue within the period: MFMA A, MFMA B, epi A (VALU
//     overlaps B's matrix-pipe drain), epi B  (R10-proven, zero barriers)
//   - chunk = 16KB contiguous in Xs (two adjacent 64-groups) -> linear
//     4x gll16 staging unchanged in structure
// Kept verbatim: pre-swizzled Xs + linear gll16 (rule 21), swizzled
// ds_read slot=(bh*4+g)^(rr&7), C-operand alpha (acc = a4 + a4*x.X),
// packed f32v2 epilogue (compiler v_pk_*, no inline asm -- R13),
// s_setprio around MFMA clusters, alpha prefetch one chunk ahead,
// BM=256/MT=4 (R18 lever), partials+finalize (no atomics -- R7).
// Grid 512 = 2 blocks/CU at launch_bounds(256,2); VGPR ~225 (<=256).

typedef __attribute__((ext_vector_type(8))) short bf16x8;
typedef __attribute__((ext_vector_type(8))) unsigned short ushort8;
typedef __attribute__((ext_vector_type(4))) float f32x4;
typedef __attribute__((ext_vector_type(2))) float f32v2;

#define MM 16384
#define NN 8192
#define DD 64
#define NSPLIT 8           // n-splits -> partial slices
#define CHUNK 128          // n-cols per LDS chunk (two 64-col halves)
#define CHUNKS_PER_BLK 8   // 8192 / (8*128)
#define BM 256             // m-rows per block
#define MT 4               // m-tiles per wave (64 rows)

__device__ __forceinline__ unsigned short f2bf(float f) {
    uint32_t u = __float_as_uint(f);
    uint32_t r = (u + 0x7FFFu + ((u >> 16) & 1u)) >> 16;  // RNE
    return (unsigned short)r;
}

__device__ __forceinline__ void gll16(const void* g, void* l) {
    __builtin_amdgcn_global_load_lds(
        (const __attribute__((address_space(1))) unsigned int*)g,
        (__attribute__((address_space(3))) unsigned int*)l, 16, 0, 0);
}

// xp -> xbf linear row-major [16384][64] bf16.
// X  -> Xs swizzled: element (n,k) at shorts:
//   (n>>6)*4096 + (n&63)*64 + ((k>>3) ^ (n&7))*8 + (k&7),  prescaled by a4[n].
// alpha4f[n] = alpha[n]^(1/4).
__global__ void convert_kernel(const float* __restrict__ xp,
                               const float* __restrict__ X,
                               const float* __restrict__ alpha,
                               unsigned short* __restrict__ xbf,
                               unsigned short* __restrict__ Xs,
                               float* __restrict__ alpha4f) {
    const int xp4 = MM * DD / 4;          // 262144 float4 units
    const int xu = NN * DD / 8;           // 65536 16B units
    const int tot = xp4 + xu;
    int tid0 = blockIdx.x * blockDim.x + threadIdx.x;
    if (tid0 < NN) alpha4f[tid0] = sqrtf(sqrtf(alpha[tid0]));
    int stride = gridDim.x * blockDim.x;
    for (int i = tid0; i < tot; i += stride) {
        if (i < xp4) {
            float4 v = ((const float4*)xp)[i];
            ushort4 o;
            o.x = f2bf(v.x); o.y = f2bf(v.y); o.z = f2bf(v.z); o.w = f2bf(v.w);
            *(ushort4*)(xbf + (size_t)i * 4) = o;
        } else {
            int u = i - xp4;
            int n = u >> 3;
            int slot = u & 7;
            float a4 = sqrtf(sqrtf(alpha[n]));
            float4 va = ((const float4*)X)[n * 16 + slot * 2];
            float4 vb = ((const float4*)X)[n * 16 + slot * 2 + 1];
            ushort8 o;
            o[0] = f2bf(va.x * a4); o[1] = f2bf(va.y * a4);
            o[2] = f2bf(va.z * a4); o[3] = f2bf(va.w * a4);
            o[4] = f2bf(vb.x * a4); o[5] = f2bf(vb.y * a4);
            o[6] = f2bf(vb.z * a4); o[7] = f2bf(vb.w * a4);
            size_t dst = (size_t)(n >> 6) * 4096 + (n & 63) * 64
                       + ((slot ^ (n & 7)) * 8);
            *(ushort8*)(Xs + dst) = o;
        }
    }
}

// Stage 16KB chunk CL (block-local) into LDS buffer (CL&1): 4 linear gll16
#define STAGE(CL)                                                         \
    {                                                                     \
        const char* gs = (const char*)Xs                                  \
            + (size_t)(chunk0 + (CL)) * 16384 + tid * 16;                 \
        char* lb = smem + ((CL) & 1) * 16384 + w * 1024;                  \
        _Pragma("unroll")                                                 \
        for (int j = 0; j < 4; ++j)                                       \
            gll16(gs + j * 4096, lb + j * 4096);                          \
    }

// Read B fragments + issue 32 MFMA for half H of buffer `bufp` into ACC
#define HALF_MFMA(H, ACC, AV)                                             \
    {                                                                     \
        bf16x8 b[4][2];                                                   \
        _Pragma("unroll")                                                 \
        for (int nt = 0; nt < 4; ++nt) {                                  \
            const int rr = nt * 16 + r;                                   \
            const char* rowp = bufp + (H) * 8192 + rr * 128;              \
            _Pragma("unroll")                                             \
            for (int bh = 0; bh < 2; ++bh) {                              \
                const int slot = (bh * 4 + g) ^ (rr & 7);                 \
                b[nt][bh] = *(const bf16x8*)(rowp + slot * 16);           \
            }                                                             \
        }                                                                 \
        f32x4 cav[4];                                                     \
        _Pragma("unroll")                                                 \
        for (int nt = 0; nt < 4; ++nt)                                    \
            cav[nt] = (f32x4){AV[nt], AV[nt], AV[nt], AV[nt]};            \
        __builtin_amdgcn_s_setprio(1);                                    \
        _Pragma("unroll")                                                 \
        for (int nt = 0; nt < 4; ++nt)                                    \
            _Pragma("unroll")                                             \
            for (int mt = 0; mt < MT; ++mt)                               \
                ACC[mt][nt] = __builtin_amdgcn_mfma_f32_16x16x32_bf16(    \
                    a[mt][0], b[nt][0], cav[nt], 0, 0, 0);                \
        _Pragma("unroll")                                                 \
        for (int nt = 0; nt < 4; ++nt)                                    \
            _Pragma("unroll")                                             \
            for (int mt = 0; mt < MT; ++mt)                               \
                ACC[mt][nt] = __builtin_amdgcn_mfma_f32_16x16x32_bf16(    \
                    a[mt][1], b[nt][1], ACC[mt][nt], 0, 0, 0);            \
        __builtin_amdgcn_s_setprio(0);                                    \
    }

#define EPILOGUE(ACC)                                                     \
    {                                                                     \
        _Pragma("unroll")                                                 \
        for (int mt = 0; mt < MT; ++mt)                                   \
            _Pragma("unroll")                                             \
            for (int nt = 0; nt < 4; ++nt) {                              \
                f32v2 lo = (f32v2){ACC[mt][nt][0], ACC[mt][nt][1]};       \
                f32v2 hi = (f32v2){ACC[mt][nt][2], ACC[mt][nt][3]};       \
                f32v2 lo2 = lo * lo;                                      \
                f32v2 hi2 = hi * hi;                                      \
                red2[mt][0] = lo2 * lo2 + red2[mt][0];                    \
                red2[mt][1] = hi2 * hi2 + red2[mt][1];                    \
            }                                                             \
    }

__global__ __launch_bounds__(256, 2) void svr_main(
        const unsigned short* __restrict__ xbf,
        const unsigned short* __restrict__ Xs,
        const float* __restrict__ alpha4f,
        float* __restrict__ partials) {
    __shared__ char smem[34816];          // 2 x 16KB chunk buffers + 2KB sred
    const int tid  = threadIdx.x;
    const int lane = tid & 63;
    const int w    = tid >> 6;            // wave 0..3, owns rows [w*64, w*64+64)
    const int r    = lane & 15;           // row-in-tile / col-in-tile
    const int g    = lane >> 4;           // k-slice selector
    const int mgroup = blockIdx.x >> 3;   // 0..63
    const int ns     = blockIdx.x & 7;    // 0..7

    // A fragments: 4 m-tiles x 2 k-slices, regs for whole kernel (32 VGPR)
    bf16x8 a[MT][2];
#pragma unroll
    for (int mt = 0; mt < MT; ++mt)
#pragma unroll
        for (int ks = 0; ks < 2; ++ks)
            a[mt][ks] = *(const bf16x8*)(
                xbf + (size_t)(mgroup * BM + w * 64 + mt * 16 + r) * DD
                    + ks * 32 + g * 8);

    f32v2 red2[MT][2];
#pragma unroll
    for (int mt = 0; mt < MT; ++mt) {
        red2[mt][0] = (f32v2){0.f, 0.f};
        red2[mt][1] = (f32v2){0.f, 0.f};
    }

    const int chunk0 = ns * CHUNKS_PER_BLK;

    // prologue: stage chunk0; load alpha for chunk0 (both halves)
    STAGE(0);
    float avA[4], avB[4];
#pragma unroll
    for (int nt = 0; nt < 4; ++nt) {
        avA[nt] = alpha4f[chunk0 * CHUNK + nt * 16 + r];
        avB[nt] = alpha4f[chunk0 * CHUNK + 64 + nt * 16 + r];
    }
    __syncthreads();

    f32x4 accA[MT][4], accB[MT][4];

#pragma unroll 1
    for (int c = 0; c < CHUNKS_PER_BLK; ++c) {
        float avAn[4], avBn[4];
        if (c + 1 < CHUNKS_PER_BLK) {      // stage next chunk + its alpha
            STAGE(c + 1);
#pragma unroll
            for (int nt = 0; nt < 4; ++nt) {
                avAn[nt] = alpha4f[(chunk0 + c + 1) * CHUNK + nt * 16 + r];
                avBn[nt] = alpha4f[(chunk0 + c + 1) * CHUNK + 64 + nt * 16 + r];
            }
        }
        const char* bufp = smem + (c & 1) * 16384;
        HALF_MFMA(0, accA, avA);           // 32 MFMA into accA
        HALF_MFMA(1, accB, avB);           // 32 MFMA into accB
        EPILOGUE(accA);                    // VALU overlaps B's pipe drain
        EPILOGUE(accB);
        __syncthreads();
        if (c + 1 < CHUNKS_PER_BLK) {
#pragma unroll
            for (int nt = 0; nt < 4; ++nt) {
                avA[nt] = avAn[nt];
                avB[nt] = avBn[nt];
            }
        }
    }

    // reduce across the 16 column-lanes (r); rows live at g*4+i per m-tile
#pragma unroll
    for (int mt = 0; mt < MT; ++mt)
#pragma unroll
        for (int i = 0; i < 4; ++i) {
            float v = red2[mt][i >> 1][i & 1];
            v += __shfl_xor(v, 1);
            v += __shfl_xor(v, 2);
            v += __shfl_xor(v, 4);
            v += __shfl_xor(v, 8);
            if (r == 0) {
                int row = mgroup * BM + w * 64 + mt * 16 + g * 4 + i;
                partials[(size_t)ns * MM + row] = v;
            }
        }
}

__global__ void finalize_kernel(const float* __restrict__ partials,
                                const float* __restrict__ bbias,
                                float* __restrict__ out) {
    int m = blockIdx.x * blockDim.x + threadIdx.x;
    if (m < MM) {
        float s = bbias[0];
#pragma unroll
        for (int c = 0; c < NSPLIT; ++c) s += partials[(size_t)c * MM + m];
        out[m] = s;
    }
}

extern "C" void kernel_launch(void* const* d_in, const int* in_sizes, int n_in,
                              void* d_out, int out_size, void* d_ws, size_t ws_size,
                              hipStream_t stream) {
    const float* xp    = (const float*)d_in[0];
    const float* X     = (const float*)d_in[1];
    const float* alpha = (const float*)d_in[2];
    const float* b     = (const float*)d_in[3];
    float* out = (float*)d_out;

    // ws: xbf 2MB | Xs 1MB | alpha4f 32KB | partials 8*16384*4 = 512KB
    unsigned short* xbf = (unsigned short*)d_ws;
    unsigned short* Xs  = xbf + (size_t)MM * DD;
    float* alpha4f = (float*)(Xs + (size_t)NN * DD);
    float* partials = alpha4f + NN;

    hipLaunchKernelGGL(convert_kernel, dim3(1280), dim3(256), 0, stream,
                       xp, X, alpha, xbf, Xs, alpha4f);

    hipLaunchKernelGGL(svr_main, dim3((MM / BM) * NSPLIT), dim3(256), 0, stream,
                       xbf, Xs, alpha4f, partials);

    hipLaunchKernelGGL(finalize_kernel, dim3(MM / 256), dim3(256), 0, stream,
                       partials, b, out);
}

// Round 20
// 31.876 us; speedup vs baseline: 1.0228x; 1.0228x over previous
//
#include <hip/hip_runtime.h>
#include <hip/hip_bf16.h>
#include <stdint.h>

// SVR polynomial-kernel prediction:
//   out[m] = sum_n alpha[n] * (1 + x_p[m].X[n])^4 + b
// m=16384, n=8192, d=64, all fp32 in/out.
// R20 = R18 geometry (best, 31.9us: BM=256/MT=4, NSPLIT=8, grid 512 =
// 2 blocks/CU) + faithful T3+T4 2-phase-per-chunk schedule:
//   phase(c,h): stage 1 gll16 of (c+1,h) -> "s_waitcnt vmcnt(2); s_barrier"
//   (single memory-clobbered asm: nothing crosses) -> ds_read 4xb128 for
//   col-half h -> setprio(1) 16 MFMA setprio(0) -> deferred epilogue of
//   previous phase's acc (ping-pong, VALU overlaps MFMA drain) -> s_barrier.
//   vmcnt NEVER 0 in steady state (count: queue=[c.h, c.other, new]->2);
//   last chunk peeled with vmcnt(1)/vmcnt(0). 8 MFMA/barrier = m201 density.
//   alpha staged to LDS in prologue -> loop's only VMEM is the gll16
//   (hand count exact); alpha reads become ds_read (lgkmcnt).
// Kept verbatim: pre-swizzled Xs + linear gll16 (rule 21), swizzled
// ds_read slot=(bh*4+g)^(rr&7), C-operand alpha (acc = a4 + a4*x.X),
// packed f32v2 epilogue (compiler v_pk_*, no inline asm -- R13),
// xbf staging, partials+finalize (no atomics -- R7).

typedef __attribute__((ext_vector_type(8))) short bf16x8;
typedef __attribute__((ext_vector_type(8))) unsigned short ushort8;
typedef __attribute__((ext_vector_type(4))) float f32x4;
typedef __attribute__((ext_vector_type(2))) float f32v2;

#define MM 16384
#define NN 8192
#define DD 64
#define NSPLIT 8           // n-splits -> partial slices
#define CHUNK 64           // n-cols per LDS chunk
#define CPB 16             // chunks per block: 8192 / (8*64)
#define BM 256             // m-rows per block
#define MT 4               // m-tiles per wave (64 rows)

__device__ __forceinline__ unsigned short f2bf(float f) {
    uint32_t u = __float_as_uint(f);
    uint32_t r = (u + 0x7FFFu + ((u >> 16) & 1u)) >> 16;  // RNE
    return (unsigned short)r;
}

__device__ __forceinline__ void gll16(const void* g, void* l) {
    __builtin_amdgcn_global_load_lds(
        (const __attribute__((address_space(1))) unsigned int*)g,
        (__attribute__((address_space(3))) unsigned int*)l, 16, 0, 0);
}

// xp -> xbf linear row-major [16384][64] bf16.
// X  -> Xs swizzled: element (n,k) at shorts:
//   (n>>6)*4096 + (n&63)*64 + ((k>>3) ^ (n&7))*8 + (k&7),  prescaled by a4[n].
// alpha4f[n] = alpha[n]^(1/4).
__global__ void convert_kernel(const float* __restrict__ xp,
                               const float* __restrict__ X,
                               const float* __restrict__ alpha,
                               unsigned short* __restrict__ xbf,
                               unsigned short* __restrict__ Xs,
                               float* __restrict__ alpha4f) {
    const int xp4 = MM * DD / 4;          // 262144 float4 units
    const int xu = NN * DD / 8;           // 65536 16B units
    const int tot = xp4 + xu;
    int tid0 = blockIdx.x * blockDim.x + threadIdx.x;
    if (tid0 < NN) alpha4f[tid0] = sqrtf(sqrtf(alpha[tid0]));
    int stride = gridDim.x * blockDim.x;
    for (int i = tid0; i < tot; i += stride) {
        if (i < xp4) {
            float4 v = ((const float4*)xp)[i];
            ushort4 o;
            o.x = f2bf(v.x); o.y = f2bf(v.y); o.z = f2bf(v.z); o.w = f2bf(v.w);
            *(ushort4*)(xbf + (size_t)i * 4) = o;
        } else {
            int u = i - xp4;
            int n = u >> 3;
            int slot = u & 7;
            float a4 = sqrtf(sqrtf(alpha[n]));
            float4 va = ((const float4*)X)[n * 16 + slot * 2];
            float4 vb = ((const float4*)X)[n * 16 + slot * 2 + 1];
            ushort8 o;
            o[0] = f2bf(va.x * a4); o[1] = f2bf(va.y * a4);
            o[2] = f2bf(va.z * a4); o[3] = f2bf(va.w * a4);
            o[4] = f2bf(vb.x * a4); o[5] = f2bf(vb.y * a4);
            o[6] = f2bf(vb.z * a4); o[7] = f2bf(vb.w * a4);
            size_t dst = (size_t)(n >> 6) * 4096 + (n & 63) * 64
                       + ((slot ^ (n & 7)) * 8);
            *(ushort8*)(Xs + dst) = o;
        }
    }
}

#define EPI(ACC)                                                          \
    {                                                                     \
        _Pragma("unroll")                                                 \
        for (int mt = 0; mt < MT; ++mt)                                   \
            _Pragma("unroll")                                             \
            for (int q = 0; q < 2; ++q) {                                 \
                f32v2 lo = (f32v2){ACC[mt][q][0], ACC[mt][q][1]};         \
                f32v2 hi = (f32v2){ACC[mt][q][2], ACC[mt][q][3]};         \
                f32v2 lo2 = lo * lo;                                      \
                f32v2 hi2 = hi * hi;                                      \
                red2[mt][0] = lo2 * lo2 + red2[mt][0];                    \
                red2[mt][1] = hi2 * hi2 + red2[mt][1];                    \
            }                                                             \
    }

// One phase: col-half H of chunk C. Stage (C+1,H) if DOSTAGE; counted
// vmcnt+barrier in ONE memory-clobbered asm (nothing memory crosses it);
// ds_read half; 16 MFMA under setprio; deferred epilogue of PACC.
#define PHASE_BODY(C, H, ACC, PACC, DOPREV, DOSTAGE, VC)                  \
    {                                                                     \
        if (DOSTAGE) {                                                    \
            const char* gsp = (const char*)Xs                             \
                + (size_t)(chunk0 + (C) + 1) * 8192 + (H) * 4096          \
                + tid * 16;                                               \
            char* lbp = smem + (((C) + 1) & 1) * 8192 + (H) * 4096        \
                + w * 1024;                                               \
            gll16(gsp, lbp);                                              \
        }                                                                 \
        asm volatile("s_waitcnt vmcnt(" #VC ")\n\ts_barrier"              \
                     ::: "memory");                                       \
        const char* buf = smem + ((C) & 1) * 8192;                        \
        float avq0 = alda[(C) * 64 + (2 * (H)) * 16 + r];                 \
        float avq1 = alda[(C) * 64 + (2 * (H) + 1) * 16 + r];             \
        bf16x8 b[2][2];                                                   \
        _Pragma("unroll")                                                 \
        for (int nt2 = 0; nt2 < 2; ++nt2) {                               \
            const int rr = (2 * (H) + nt2) * 16 + r;                      \
            const char* rowp = buf + rr * 128;                            \
            _Pragma("unroll")                                             \
            for (int bh = 0; bh < 2; ++bh)                                \
                b[nt2][bh] = *(const bf16x8*)(                            \
                    rowp + (((bh * 4 + g) ^ (rr & 7)) * 16));             \
        }                                                                 \
        f32x4 cav0 = (f32x4){avq0, avq0, avq0, avq0};                     \
        f32x4 cav1 = (f32x4){avq1, avq1, avq1, avq1};                     \
        __builtin_amdgcn_s_setprio(1);                                    \
        _Pragma("unroll")                                                 \
        for (int mt = 0; mt < MT; ++mt) {                                 \
            ACC[mt][0] = __builtin_amdgcn_mfma_f32_16x16x32_bf16(         \
                a[mt][0], b[0][0], cav0, 0, 0, 0);                        \
            ACC[mt][1] = __builtin_amdgcn_mfma_f32_16x16x32_bf16(         \
                a[mt][0], b[1][0], cav1, 0, 0, 0);                        \
        }                                                                 \
        _Pragma("unroll")                                                 \
        for (int mt = 0; mt < MT; ++mt) {                                 \
            ACC[mt][0] = __builtin_amdgcn_mfma_f32_16x16x32_bf16(         \
                a[mt][1], b[0][1], ACC[mt][0], 0, 0, 0);                  \
            ACC[mt][1] = __builtin_amdgcn_mfma_f32_16x16x32_bf16(         \
                a[mt][1], b[1][1], ACC[mt][1], 0, 0, 0);                  \
        }                                                                 \
        __builtin_amdgcn_s_setprio(0);                                    \
        if (DOPREV) EPI(PACC);                                            \
        asm volatile("s_barrier" ::: "memory");                           \
    }

__global__ __launch_bounds__(256, 2) void svr_main(
        const unsigned short* __restrict__ xbf,
        const unsigned short* __restrict__ Xs,
        const float* __restrict__ alpha4f,
        float* __restrict__ partials) {
    // LDS: [0,16384) 2x8KB chunk dbuf | [16384,20480) alpha slice (1024 f32)
    __shared__ char smem[20480];
    const int tid  = threadIdx.x;
    const int lane = tid & 63;
    const int w    = tid >> 6;            // wave 0..3, owns rows [w*64, w*64+64)
    const int r    = lane & 15;           // row-in-tile / col-in-tile
    const int g    = lane >> 4;           // k-slice selector
    const int mgroup = blockIdx.x >> 3;   // 0..63
    const int ns     = blockIdx.x & 7;    // 0..7
    const int chunk0 = ns * CPB;

    // A fragments: 4 m-tiles x 2 k-slices, regs for whole kernel
    bf16x8 a[MT][2];
#pragma unroll
    for (int mt = 0; mt < MT; ++mt)
#pragma unroll
        for (int ks = 0; ks < 2; ++ks)
            a[mt][ks] = *(const bf16x8*)(
                xbf + (size_t)(mgroup * BM + w * 64 + mt * 16 + r) * DD
                    + ks * 32 + g * 8);

    f32v2 red2[MT][2];
#pragma unroll
    for (int mt = 0; mt < MT; ++mt) {
        red2[mt][0] = (f32v2){0.f, 0.f};
        red2[mt][1] = (f32v2){0.f, 0.f};
    }

    // prologue: stage alpha slice (4KB) + chunk0 (8KB); __syncthreads
    // drains vmcnt to 0 -> hand count in the loop is exact.
    {
        const char* ga = (const char*)(alpha4f + chunk0 * CHUNK) + tid * 16;
        char* la = smem + 16384 + w * 1024;
        gll16(ga, la);
        const char* gs = (const char*)Xs + (size_t)chunk0 * 8192 + tid * 16;
        char* lb = smem + w * 1024;
        gll16(gs, lb);
        gll16(gs + 4096, lb + 4096);
    }
    __syncthreads();

    const float* alda = (const float*)(smem + 16384);
    f32x4 accE[MT][2], accO[MT][2];

#pragma unroll 1
    for (int c = 0; c < CPB - 1; ++c) {
        PHASE_BODY(c, 0, accE, accO, (c > 0), true, 2);
        PHASE_BODY(c, 1, accO, accE, true, true, 2);
    }
    {
        const int c = CPB - 1;
        PHASE_BODY(c, 0, accE, accO, true, false, 1);
        PHASE_BODY(c, 1, accO, accE, true, false, 0);
    }
    EPI(accO);   // trailing: last phase's accumulators

    // reduce across the 16 column-lanes (r); rows live at g*4+i per m-tile
#pragma unroll
    for (int mt = 0; mt < MT; ++mt)
#pragma unroll
        for (int i = 0; i < 4; ++i) {
            float v = red2[mt][i >> 1][i & 1];
            v += __shfl_xor(v, 1);
            v += __shfl_xor(v, 2);
            v += __shfl_xor(v, 4);
            v += __shfl_xor(v, 8);
            if (r == 0) {
                int row = mgroup * BM + w * 64 + mt * 16 + g * 4 + i;
                partials[(size_t)ns * MM + row] = v;
            }
        }
}

__global__ void finalize_kernel(const float* __restrict__ partials,
                                const float* __restrict__ bbias,
                                float* __restrict__ out) {
    int m = blockIdx.x * blockDim.x + threadIdx.x;
    if (m < MM) {
        float s = bbias[0];
#pragma unroll
        for (int c = 0; c < NSPLIT; ++c) s += partials[(size_t)c * MM + m];
        out[m] = s;
    }
}

extern "C" void kernel_launch(void* const* d_in, const int* in_sizes, int n_in,
                              void* d_out, int out_size, void* d_ws, size_t ws_size,
                              hipStream_t stream) {
    const float* xp    = (const float*)d_in[0];
    const float* X     = (const float*)d_in[1];
    const float* alpha = (const float*)d_in[2];
    const float* b     = (const float*)d_in[3];
    float* out = (float*)d_out;

    // ws: xbf 2MB | Xs 1MB | alpha4f 32KB | partials 8*16384*4 = 512KB
    unsigned short* xbf = (unsigned short*)d_ws;
    unsigned short* Xs  = xbf + (size_t)MM * DD;
    float* alpha4f = (float*)(Xs + (size_t)NN * DD);
    float* partials = alpha4f + NN;

    hipLaunchKernelGGL(convert_kernel, dim3(1280), dim3(256), 0, stream,
                       xp, X, alpha, xbf, Xs, alpha4f);

    hipLaunchKernelGGL(svr_main, dim3((MM / BM) * NSPLIT), dim3(256), 0, stream,
                       xbf, Xs, alpha4f, partials);

    hipLaunchKernelGGL(finalize_kernel, dim3(MM / 256), dim3(256), 0, stream,
                       partials, b, out);
}